// Round 3
// baseline (1057.321 us; speedup 1.0000x reference)
//
#include <hip/hip_runtime.h>

// ---------------------------------------------------------------------------
// SymmetricCrossAttention, B=4, C=64, H=W=256, HEADS=1.
// out1 = M1 X2 + c1 + X1, out2 = M2 X1 + c2 + X2 with M,c derived from
// G12 = X1 X2^T (64x64 per batch) + channel sums (k_gram/k_reduce/k_mid).
// R3: k_apply -> LDS-staged, wave-uniform M chunks (s_load path), acc[16]
//     only, full occupancy, no global re-reads (was scratch-spilled 153us).
//     k_gram -> VGPR<=128 (stream a_i vs resident bb[8]), 4 waves/SIMD.
// ---------------------------------------------------------------------------

#define NPIX 65536
#define SCALE 0.125f
#define NBLK_GRAM 512      // 4 batches * 128 chunks (512 px each)

// workspace float offsets
#define GP_OFF  0                      // 512 * 4096 partial Grams
#define SP_OFF  2097152                // 512 * 128 partial channel sums (s1|s2)
#define G_OFF   2162688                // 4 * 4096
#define S1_OFF  2179072                // 4 * 64
#define S2_OFF  2179328                // 4 * 64
#define MT_OFF  2179584                // 2*4*4096, M stored transposed Mt[j][o]
#define CV_OFF  2212352                // 2*4*64
#define WS_FLOATS 2212864              // ~8.85 MB

// ---- XOR-swizzled 64x64 fp32 LDS tile helpers (16B-block index ^ (row>>2)&7)
__device__ __forceinline__ int swzidx(int row, int k) {
  return (row << 6) + ((((k >> 2) ^ ((row >> 2) & 7)) << 2) | (k & 3));
}
__device__ __forceinline__ float ldswz1(const float* b, int row, int k) {
  return b[swzidx(row, k)];
}
__device__ __forceinline__ void stswz1(float* b, int row, int k, float v) {
  b[swzidx(row, k)] = v;
}
__device__ __forceinline__ float4 ldswz4f(const float* b, int row, int k) { // k%4==0
  return *(const float4*)(b + (row << 6) + ((((k >> 2) ^ ((row >> 2) & 7)) << 2)));
}
__device__ __forceinline__ void stswz4f(float* b, int row, int k, float4 v) {
  *(float4*)(b + (row << 6) + ((((k >> 2) ^ ((row >> 2) & 7)) << 2))) = v;
}

// ---- cross-wave accumulator exchange (rotated to spread banks)
__device__ __forceinline__ float* redptr(float* base, int l, int m) {
  return base + (l << 6) + (((m + l) & 15) << 2);
}
__device__ __forceinline__ void red_store(float* base, int l, const float acc[8][8]) {
#pragma unroll
  for (int m = 0; m < 16; ++m) {
    const int i = m >> 1, j0 = (m & 1) << 2;
    *(float4*)redptr(base, l, m) =
        make_float4(acc[i][j0], acc[i][j0 + 1], acc[i][j0 + 2], acc[i][j0 + 3]);
  }
}
__device__ __forceinline__ void red_add(const float* base, int l, float acc[8][8]) {
#pragma unroll
  for (int m = 0; m < 16; ++m) {
    const int i = m >> 1, j0 = (m & 1) << 2;
    const float4 v = *(const float4*)redptr(const_cast<float*>(base), l, m);
    acc[i][j0] += v.x; acc[i][j0 + 1] += v.y; acc[i][j0 + 2] += v.z; acc[i][j0 + 3] += v.w;
  }
}

// ---------------------------------------------------------------------------
// Gram kernel: per batch, G12 = X1 X2^T (64x64) + channel sums.
// 512 blocks = 4 batches * 128 chunks; chunk = 512 px = 8 tiles of 64 px.
// 4 waves split-k (16 px each); 8x8 acc per lane; bb[8] resident, a_i
// streamed (VGPR <= 128 -> 4 waves/SIMD). Cross-wave LDS reduce; no atomics.
__global__ __launch_bounds__(256, 4) void k_gram(const float* __restrict__ x1,
                                                 const float* __restrict__ x2,
                                                 float* __restrict__ gp,
                                                 float* __restrict__ sp) {
  __shared__ __align__(16) float A[4096];   // X1 tile [64ch][64px], swizzled
  __shared__ __align__(16) float Bt[4096];  // X2 tile
  const int tid = threadIdx.x;
  const int b = blockIdx.x >> 7;
  const int chunk = blockIdx.x & 127;
  const size_t base = ((size_t)b << 22) + ((size_t)chunk << 9);

  const int w = tid >> 6;          // wave 0..3 -> k-slice
  const int l = tid & 63;
  const int r0 = (l >> 3) << 3;    // 8 rows of G
  const int c0 = (l & 7) << 3;     // 8 cols of G

  float acc[8][8] = {{0.f}};
  float sum1[4] = {0.f, 0.f, 0.f, 0.f};
  float sum2[4] = {0.f, 0.f, 0.f, 0.f};

  for (int t = 0; t < 8; ++t) {
    __syncthreads();  // protect LDS from previous iteration's readers
#pragma unroll
    for (int r = 0; r < 4; ++r) {
      const int idx = (r << 8) + tid;
      const int c = idx >> 4;         // channel row
      const int p4 = idx & 15;        // pixel float4 block
      const size_t g = base + ((size_t)c << 16) + (t << 6) + (p4 << 2);
      const float4 v1 = *(const float4*)(x1 + g);
      const float4 v2 = *(const float4*)(x2 + g);
      stswz4f(A, c, p4 << 2, v1);
      stswz4f(Bt, c, p4 << 2, v2);
      sum1[r] += v1.x + v1.y + v1.z + v1.w;
      sum2[r] += v2.x + v2.y + v2.z + v2.w;
    }
    __syncthreads();
#pragma unroll
    for (int s = 0; s < 4; ++s) {
      const int kb = (w << 4) + (s << 2);
      float4 bb[8];
#pragma unroll
      for (int j = 0; j < 8; ++j) bb[j] = ldswz4f(Bt, c0 + j, kb);
#pragma unroll
      for (int i = 0; i < 8; ++i) {
        const float4 ai = ldswz4f(A, r0 + i, kb);
#pragma unroll
        for (int j = 0; j < 8; ++j) {
          acc[i][j] += ai.x * bb[j].x + ai.y * bb[j].y +
                       ai.z * bb[j].z + ai.w * bb[j].w;
        }
      }
    }
  }

  // channel sums -> per-block partial (16 consecutive lanes share a channel)
  float* spb = sp + (blockIdx.x << 7);
#pragma unroll
  for (int r = 0; r < 4; ++r) {
    const int c = ((r << 8) + tid) >> 4;
    float v1 = sum1[r], v2 = sum2[r];
#pragma unroll
    for (int d = 8; d >= 1; d >>= 1) {
      v1 += __shfl_down(v1, d, 16);
      v2 += __shfl_down(v2, d, 16);
    }
    if ((tid & 15) == 0) {
      spb[c] = v1;
      spb[64 + c] = v2;
    }
  }

  // cross-wave k-reduction (lane-aligned acc regions), reusing tile LDS
  __syncthreads();
  if (w == 1) red_store(A, l, acc);
  if (w == 3) red_store(Bt, l, acc);
  __syncthreads();
  if (w == 0) red_add(A, l, acc);
  if (w == 2) red_add(Bt, l, acc);
  __syncthreads();
  if (w == 2) red_store(A, l, acc);
  __syncthreads();
  if (w == 0) {
    red_add(A, l, acc);
    float* g = gp + ((size_t)blockIdx.x << 12);
#pragma unroll
    for (int i = 0; i < 8; ++i) {
      *(float4*)(g + ((r0 + i) << 6) + c0) =
          make_float4(acc[i][0], acc[i][1], acc[i][2], acc[i][3]);
      *(float4*)(g + ((r0 + i) << 6) + c0 + 4) =
          make_float4(acc[i][4], acc[i][5], acc[i][6], acc[i][7]);
    }
  }
}

// ---------------------------------------------------------------------------
// Reduce 128 partials per batch into final G and channel sums.
__global__ __launch_bounds__(256) void k_reduce(float* __restrict__ ws) {
  const int g = blockIdx.x;
  const int tid = threadIdx.x;
  if (g < 64) {
    const int idx = (g << 8) + tid;            // 0..16383
    const int b = idx >> 12, e = idx & 4095;
    const float* p = ws + GP_OFF + (((size_t)b << 7) << 12) + e;
    float a = 0.f;
#pragma unroll 8
    for (int k = 0; k < 128; ++k) a += p[(size_t)k << 12];
    ws[G_OFF + idx] = a;
  } else {
    const int b = g - 64;
    if (tid < 128) {
      const float* p = ws + SP_OFF + ((b << 7) << 7) + tid;
      float a = 0.f;
#pragma unroll 8
      for (int k = 0; k < 128; ++k) a += p[k << 7];
      if (tid < 64) ws[S1_OFF + (b << 6) + tid] = a;
      else          ws[S2_OFF + (b << 6) + (tid - 64)] = a;
    }
  }
}

// ---------------------------------------------------------------------------
// 64x64 fp32 matmul in swizzled LDS. D[c][d] = sum_k A[c][k] * (TRANSB ? B[d][k] : B[k][d])
template <bool TRANSB>
__device__ __forceinline__ void mm64(const float* __restrict__ A, const float* __restrict__ B,
                                     float* __restrict__ D, int tid) {
  const int c0 = (tid >> 4) << 2;
  const int d0 = (tid & 15) << 2;
  float acc[4][4] = {{0.f}};
#pragma unroll
  for (int kb = 0; kb < 64; kb += 4) {
    float4 a[4];
#pragma unroll
    for (int i = 0; i < 4; ++i) a[i] = ldswz4f(A, c0 + i, kb);
    if (TRANSB) {
#pragma unroll
      for (int j = 0; j < 4; ++j) {
        const float4 bj = ldswz4f(B, d0 + j, kb);
#pragma unroll
        for (int i = 0; i < 4; ++i) {
          acc[i][j] += a[i].x * bj.x + a[i].y * bj.y + a[i].z * bj.z + a[i].w * bj.w;
        }
      }
    } else {
#pragma unroll
      for (int r = 0; r < 4; ++r) {
        const float4 q = ldswz4f(B, kb + r, d0);
        const float br[4] = {q.x, q.y, q.z, q.w};
#pragma unroll
        for (int i = 0; i < 4; ++i) {
          const float av = (r == 0) ? a[i].x : (r == 1) ? a[i].y : (r == 2) ? a[i].z : a[i].w;
#pragma unroll
          for (int j = 0; j < 4; ++j) acc[i][j] += av * br[j];
        }
      }
    }
  }
#pragma unroll
  for (int i = 0; i < 4; ++i) {
    stswz4f(D, c0 + i, d0, make_float4(acc[i][0], acc[i][1], acc[i][2], acc[i][3]));
  }
}

// M = A @ B (non-trans), stored TRANSPOSED to global: Mt[j][o] = M[o][j]
__device__ __forceinline__ void mm64_storeT(const float* __restrict__ A, const float* __restrict__ B,
                                            float* __restrict__ Mt, int tid) {
  const int c0 = (tid >> 4) << 2;
  const int d0 = (tid & 15) << 2;
  float acc[4][4] = {{0.f}};
#pragma unroll
  for (int kb = 0; kb < 64; kb += 4) {
    float4 a[4];
#pragma unroll
    for (int i = 0; i < 4; ++i) a[i] = ldswz4f(A, c0 + i, kb);
#pragma unroll
    for (int r = 0; r < 4; ++r) {
      const float4 q = ldswz4f(B, kb + r, d0);
      const float br[4] = {q.x, q.y, q.z, q.w};
#pragma unroll
      for (int i = 0; i < 4; ++i) {
        const float av = (r == 0) ? a[i].x : (r == 1) ? a[i].y : (r == 2) ? a[i].z : a[i].w;
#pragma unroll
        for (int j = 0; j < 4; ++j) acc[i][j] += av * br[j];
      }
    }
  }
#pragma unroll
  for (int i = 0; i < 4; ++i) {
#pragma unroll
    for (int j = 0; j < 4; ++j) {
      Mt[((d0 + j) << 6) + c0 + i] = acc[i][j];
    }
  }
}

__device__ __forceinline__ void load64x64(const float* __restrict__ g, float* __restrict__ lds, int tid) {
#pragma unroll
  for (int r = 0; r < 4; ++r) {
    const int idx = (r << 8) + tid;
    const int row = idx >> 4;
    const int b4 = (idx & 15) << 2;
    stswz4f(lds, row, b4, *(const float4*)(g + (row << 6) + b4));
  }
}

// ---------------------------------------------------------------------------
// Middle kernel: 8 blocks = 4 batches x 2 sides. Builds logits from G/s,
// softmax, then M (transposed) and c vectors into ws.
__global__ __launch_bounds__(256) void k_mid(
    const float* __restrict__ wq1, const float* __restrict__ bq1,
    const float* __restrict__ wk2, const float* __restrict__ bk2,
    const float* __restrict__ wv2, const float* __restrict__ bv2,
    const float* __restrict__ wo1, const float* __restrict__ bo1,
    const float* __restrict__ wq2, const float* __restrict__ bq2,
    const float* __restrict__ wk1, const float* __restrict__ bk1,
    const float* __restrict__ wv1, const float* __restrict__ bv1,
    const float* __restrict__ wo2, const float* __restrict__ bo2,
    float* __restrict__ ws) {
  __shared__ __align__(16) float LA[4096];
  __shared__ __align__(16) float LB[4096];
  __shared__ __align__(16) float LC[4096];
  __shared__ __align__(16) float LD[4096];
  __shared__ float vsq[64], vsk[64], vaq[64], vkk[64], vcv[64];

  const int tid = threadIdx.x;
  const int b = blockIdx.x >> 1;
  const int side = blockIdx.x & 1;

  const float *Wq, *Bq, *Wk, *Bk, *Wv, *Bv, *Wo, *Bo, *sqp, *skp;
  if (side == 0) {
    Wq = wq1; Bq = bq1; Wk = wk2; Bk = bk2; Wv = wv2; Bv = bv2; Wo = wo1; Bo = bo1;
    sqp = ws + S1_OFF + (b << 6); skp = ws + S2_OFF + (b << 6);
  } else {
    Wq = wq2; Bq = bq2; Wk = wk1; Bk = bk1; Wv = wv1; Bv = bv1; Wo = wo2; Bo = bo2;
    sqp = ws + S2_OFF + (b << 6); skp = ws + S1_OFF + (b << 6);
  }
  float* Mt = ws + MT_OFF + (((side << 2) + b) << 12);
  float* Cv = ws + CV_OFF + (((side << 2) + b) << 6);
  const float* G = ws + G_OFF + (b << 12);

  if (tid < 64) { vsq[tid] = sqp[tid]; vsk[tid] = skp[tid]; }
  load64x64(G, LA, tid);
  load64x64(Wq, LB, tid);
  __syncthreads();
  if (tid < 64) {  // aq = Wq @ sq
    float a = 0.f;
    for (int k = 0; k < 64; ++k) a += ldswz1(LB, tid, k) * vsq[k];
    vaq[tid] = a;
  }
  // T = Wq @ G (side0)  or  Wq @ G^T (side1)
  if (side == 0) mm64<false>(LB, LA, LC, tid);
  else           mm64<true >(LB, LA, LC, tid);
  __syncthreads();
  load64x64(Wk, LB, tid);
  __syncthreads();
  if (tid < 64) {  // kk = Wk @ sk
    float a = 0.f;
    for (int k = 0; k < 64; ++k) a += ldswz1(LB, tid, k) * vsk[k];
    vkk[tid] = a;
  }
  mm64<true>(LC, LB, LD, tid);  // S = T @ Wk^T
  __syncthreads();
  // assemble logits: S = scale*(S + aq[c]*bk[d] + bq[c]*(kk[d] + N*bk[d]))
#pragma unroll
  for (int t = 0; t < 16; ++t) {
    const int idx = (t << 8) + tid;
    const int c = idx >> 6, d = idx & 63;
    const float bkv = Bk[d], bqv = Bq[c];
    float v = ldswz1(LD, c, d);
    v = SCALE * (v + vaq[c] * bkv + bqv * (vkk[d] + 65536.f * bkv));
    stswz1(LD, c, d, v);
  }
  __syncthreads();
  {  // row softmax, 4 lanes per row
    const int row = tid >> 2, q = tid & 3;
    float ev[16];
    float mx = -3.4e38f;
#pragma unroll
    for (int t = 0; t < 16; ++t) { ev[t] = ldswz1(LD, row, q + (t << 2)); mx = fmaxf(mx, ev[t]); }
    mx = fmaxf(mx, __shfl_xor(mx, 1));
    mx = fmaxf(mx, __shfl_xor(mx, 2));
    float sm = 0.f;
#pragma unroll
    for (int t = 0; t < 16; ++t) { ev[t] = __expf(ev[t] - mx); sm += ev[t]; }
    sm += __shfl_xor(sm, 1);
    sm += __shfl_xor(sm, 2);
    const float inv = 1.f / sm;
#pragma unroll
    for (int t = 0; t < 16; ++t) stswz1(LD, row, q + (t << 2), ev[t] * inv);
  }
  __syncthreads();
  if (tid < 64) {  // cv = attn @ bv
    float a = 0.f;
    for (int d = 0; d < 64; ++d) a += ldswz1(LD, tid, d) * Bv[d];
    vcv[tid] = a;
  }
  load64x64(Wv, LB, tid);
  __syncthreads();
  mm64<false>(LD, LB, LC, tid);  // U = attn @ Wv
  __syncthreads();
  load64x64(Wo, LB, tid);
  __syncthreads();
  mm64_storeT(LB, LC, Mt, tid);  // Mt[j][o] = (Wo @ U)[o][j]
  if (tid < 64) {                // c = Wo @ cv + bo
    float a = 0.f;
    for (int c = 0; c < 64; ++c) a += ldswz1(LB, tid, c) * vcv[c];
    Cv[tid] = a + Bo[tid];
  }
}

// ---------------------------------------------------------------------------
// Apply kernel (R3): 512 thr / 8 waves / 64 px per block. Stage X1,X2 tiles
// (32KB LDS, plain [ch][px] layout -> stride-1 lane reads, 2-way free).
// Wave w: side = w>>2, out-channel chunk oc = (w&3)*16 -- wave-uniform, so
// M rows and C are scalar loads. acc[16] per thread; residual from LDS.
__global__ __launch_bounds__(512) void k_apply(const float* __restrict__ x1,
                                               const float* __restrict__ x2,
                                               const float* __restrict__ ws,
                                               float* __restrict__ out) {
  __shared__ __align__(16) float X1s[4096];  // [ch][px] 64x64
  __shared__ __align__(16) float X2s[4096];
  const int tid = threadIdx.x;
  const int b = blockIdx.x >> 10;
  const size_t ib = ((size_t)b << 22) + ((blockIdx.x & 1023) << 6);

  {  // stage both tiles: threads 0-255 -> X1, 256-511 -> X2 (wave-aligned)
    const float* src = (tid < 256) ? x1 : x2;
    float* dst = (tid < 256) ? X1s : X2s;
    const int tt = tid & 255;
    const int row = tt >> 2;                 // channel
    const int f4 = (tt & 3) << 2;            // float4 index 0,4,8,12
    const float4* g = (const float4*)(src + ib + ((size_t)row << 16)) + f4;
    float4* d = (float4*)(dst + (row << 6)) + f4;
#pragma unroll
    for (int q = 0; q < 4; ++q) d[q] = g[q];
  }
  __syncthreads();

  const int wu = __builtin_amdgcn_readfirstlane(tid >> 6);  // wave id, SGPR
  const int side = wu >> 2;
  const int oc = (wu & 3) << 4;
  const int lane = tid & 63;
  const int job = (side << 2) + b;
  const float* Mt = ws + MT_OFF + ((size_t)job << 12);  // Mt[j][o]
  const float* Cv = ws + CV_OFF + (job << 6);
  const float* Xown = side == 0 ? X1s : X2s;
  const float* Xoth = side == 0 ? X2s : X1s;

  float acc[16];
#pragma unroll
  for (int oi = 0; oi < 16; ++oi) {
    acc[oi] = Cv[oc + oi] + Xown[((oc + oi) << 6) + lane];  // c + residual
  }

#pragma unroll
  for (int j = 0; j < 64; ++j) {
    const float xv = Xoth[(j << 6) + lane];
    const float* mrow = Mt + (j << 6) + oc;   // uniform -> s_load
#pragma unroll
    for (int oi = 0; oi < 16; ++oi) acc[oi] += mrow[oi] * xv;
  }

  float* o = out + ((size_t)side << 24) + ib + ((size_t)oc << 16) + lane;
#pragma unroll
  for (int oi = 0; oi < 16; ++oi) o[(size_t)oi << 16] = acc[oi];
}

// ---------------------------------------------------------------------------
extern "C" void kernel_launch(void* const* d_in, const int* in_sizes, int n_in,
                              void* d_out, int out_size, void* d_ws, size_t ws_size,
                              hipStream_t stream) {
  const float* x1 = (const float*)d_in[0];
  const float* x2 = (const float*)d_in[1];
  float* ws = (float*)d_ws;
  float* out = (float*)d_out;

  k_gram<<<NBLK_GRAM, 256, 0, stream>>>(x1, x2, ws + GP_OFF, ws + SP_OFF);
  k_reduce<<<68, 256, 0, stream>>>(ws);
  k_mid<<<8, 256, 0, stream>>>(
      (const float*)d_in[2],  (const float*)d_in[3],   // w_q1, b_q1
      (const float*)d_in[4],  (const float*)d_in[5],   // w_k2, b_k2
      (const float*)d_in[6],  (const float*)d_in[7],   // w_v2, b_v2
      (const float*)d_in[14], (const float*)d_in[15],  // w_o1, b_o1
      (const float*)d_in[8],  (const float*)d_in[9],   // w_q2, b_q2
      (const float*)d_in[10], (const float*)d_in[11],  // w_k1, b_k1
      (const float*)d_in[12], (const float*)d_in[13],  // w_v1, b_v1
      (const float*)d_in[16], (const float*)d_in[17],  // w_o2, b_o2
      ws);
  k_apply<<<4096, 512, 0, stream>>>(x1, x2, ws, out);
}

// Round 4
// 829.025 us; speedup vs baseline: 1.2754x; 1.2754x over previous
//
#include <hip/hip_runtime.h>

// ---------------------------------------------------------------------------
// SymmetricCrossAttention, B=4, C=64, H=W=256, HEADS=1.
// out1 = M1 X2 + c1 + X1, out2 = M2 X1 + c2 + X2 with M,c derived from
// G12 = X1 X2^T (64x64 per batch) + channel sums (k_gram/k_reduce/k_mid).
// R4: k_gram launch_bounds (256,4)->(256,3). R3's bound clamped VGPR to 64
//     (< the 100+ live floats the 8x8-acc structure needs) -> full scratch
//     spill, 1.5GB scratch FETCH, 970us. Cap 170 fits the ~150 live set.
// ---------------------------------------------------------------------------

#define NPIX 65536
#define SCALE 0.125f
#define NBLK_GRAM 512      // 4 batches * 128 chunks (512 px each)

// workspace float offsets
#define GP_OFF  0                      // 512 * 4096 partial Grams
#define SP_OFF  2097152                // 512 * 128 partial channel sums (s1|s2)
#define G_OFF   2162688                // 4 * 4096
#define S1_OFF  2179072                // 4 * 64
#define S2_OFF  2179328                // 4 * 64
#define MT_OFF  2179584                // 2*4*4096, M stored transposed Mt[j][o]
#define CV_OFF  2212352                // 2*4*64
#define WS_FLOATS 2212864              // ~8.85 MB

// ---- XOR-swizzled 64x64 fp32 LDS tile helpers (16B-block index ^ (row>>2)&7)
__device__ __forceinline__ int swzidx(int row, int k) {
  return (row << 6) + ((((k >> 2) ^ ((row >> 2) & 7)) << 2) | (k & 3));
}
__device__ __forceinline__ float ldswz1(const float* b, int row, int k) {
  return b[swzidx(row, k)];
}
__device__ __forceinline__ void stswz1(float* b, int row, int k, float v) {
  b[swzidx(row, k)] = v;
}
__device__ __forceinline__ float4 ldswz4f(const float* b, int row, int k) { // k%4==0
  return *(const float4*)(b + (row << 6) + ((((k >> 2) ^ ((row >> 2) & 7)) << 2)));
}
__device__ __forceinline__ void stswz4f(float* b, int row, int k, float4 v) {
  *(float4*)(b + (row << 6) + ((((k >> 2) ^ ((row >> 2) & 7)) << 2))) = v;
}

// ---- cross-wave accumulator exchange (rotated to spread banks)
__device__ __forceinline__ float* redptr(float* base, int l, int m) {
  return base + (l << 6) + (((m + l) & 15) << 2);
}
__device__ __forceinline__ void red_store(float* base, int l, const float acc[8][8]) {
#pragma unroll
  for (int m = 0; m < 16; ++m) {
    const int i = m >> 1, j0 = (m & 1) << 2;
    *(float4*)redptr(base, l, m) =
        make_float4(acc[i][j0], acc[i][j0 + 1], acc[i][j0 + 2], acc[i][j0 + 3]);
  }
}
__device__ __forceinline__ void red_add(const float* base, int l, float acc[8][8]) {
#pragma unroll
  for (int m = 0; m < 16; ++m) {
    const int i = m >> 1, j0 = (m & 1) << 2;
    const float4 v = *(const float4*)redptr(const_cast<float*>(base), l, m);
    acc[i][j0] += v.x; acc[i][j0 + 1] += v.y; acc[i][j0 + 2] += v.z; acc[i][j0 + 3] += v.w;
  }
}

// ---------------------------------------------------------------------------
// Gram kernel: per batch, G12 = X1 X2^T (64x64) + channel sums.
// 512 blocks = 4 batches * 128 chunks; chunk = 512 px = 8 tiles of 64 px.
// 4 waves split-k (16 px each); 8x8 acc per lane; bb[8] resident, a_i
// streamed. VGPR cap 170 (3 waves/SIMD) -- fits ~150 live, no spill.
__global__ __launch_bounds__(256, 3) void k_gram(const float* __restrict__ x1,
                                                 const float* __restrict__ x2,
                                                 float* __restrict__ gp,
                                                 float* __restrict__ sp) {
  __shared__ __align__(16) float A[4096];   // X1 tile [64ch][64px], swizzled
  __shared__ __align__(16) float Bt[4096];  // X2 tile
  const int tid = threadIdx.x;
  const int b = blockIdx.x >> 7;
  const int chunk = blockIdx.x & 127;
  const size_t base = ((size_t)b << 22) + ((size_t)chunk << 9);

  const int w = tid >> 6;          // wave 0..3 -> k-slice
  const int l = tid & 63;
  const int r0 = (l >> 3) << 3;    // 8 rows of G
  const int c0 = (l & 7) << 3;     // 8 cols of G

  float acc[8][8] = {{0.f}};
  float sum1[4] = {0.f, 0.f, 0.f, 0.f};
  float sum2[4] = {0.f, 0.f, 0.f, 0.f};

  for (int t = 0; t < 8; ++t) {
    __syncthreads();  // protect LDS from previous iteration's readers
#pragma unroll
    for (int r = 0; r < 4; ++r) {
      const int idx = (r << 8) + tid;
      const int c = idx >> 4;         // channel row
      const int p4 = idx & 15;        // pixel float4 block
      const size_t g = base + ((size_t)c << 16) + (t << 6) + (p4 << 2);
      const float4 v1 = *(const float4*)(x1 + g);
      const float4 v2 = *(const float4*)(x2 + g);
      stswz4f(A, c, p4 << 2, v1);
      stswz4f(Bt, c, p4 << 2, v2);
      sum1[r] += v1.x + v1.y + v1.z + v1.w;
      sum2[r] += v2.x + v2.y + v2.z + v2.w;
    }
    __syncthreads();
#pragma unroll
    for (int s = 0; s < 4; ++s) {
      const int kb = (w << 4) + (s << 2);
      float4 bb[8];
#pragma unroll
      for (int j = 0; j < 8; ++j) bb[j] = ldswz4f(Bt, c0 + j, kb);
#pragma unroll
      for (int i = 0; i < 8; ++i) {
        const float4 ai = ldswz4f(A, r0 + i, kb);
#pragma unroll
        for (int j = 0; j < 8; ++j) {
          acc[i][j] += ai.x * bb[j].x + ai.y * bb[j].y +
                       ai.z * bb[j].z + ai.w * bb[j].w;
        }
      }
    }
  }

  // channel sums -> per-block partial (16 consecutive lanes share a channel)
  float* spb = sp + (blockIdx.x << 7);
#pragma unroll
  for (int r = 0; r < 4; ++r) {
    const int c = ((r << 8) + tid) >> 4;
    float v1 = sum1[r], v2 = sum2[r];
#pragma unroll
    for (int d = 8; d >= 1; d >>= 1) {
      v1 += __shfl_down(v1, d, 16);
      v2 += __shfl_down(v2, d, 16);
    }
    if ((tid & 15) == 0) {
      spb[c] = v1;
      spb[64 + c] = v2;
    }
  }

  // cross-wave k-reduction (lane-aligned acc regions), reusing tile LDS
  __syncthreads();
  if (w == 1) red_store(A, l, acc);
  if (w == 3) red_store(Bt, l, acc);
  __syncthreads();
  if (w == 0) red_add(A, l, acc);
  if (w == 2) red_add(Bt, l, acc);
  __syncthreads();
  if (w == 2) red_store(A, l, acc);
  __syncthreads();
  if (w == 0) {
    red_add(A, l, acc);
    float* g = gp + ((size_t)blockIdx.x << 12);
#pragma unroll
    for (int i = 0; i < 8; ++i) {
      *(float4*)(g + ((r0 + i) << 6) + c0) =
          make_float4(acc[i][0], acc[i][1], acc[i][2], acc[i][3]);
      *(float4*)(g + ((r0 + i) << 6) + c0 + 4) =
          make_float4(acc[i][4], acc[i][5], acc[i][6], acc[i][7]);
    }
  }
}

// ---------------------------------------------------------------------------
// Reduce 128 partials per batch into final G and channel sums.
__global__ __launch_bounds__(256) void k_reduce(float* __restrict__ ws) {
  const int g = blockIdx.x;
  const int tid = threadIdx.x;
  if (g < 64) {
    const int idx = (g << 8) + tid;            // 0..16383
    const int b = idx >> 12, e = idx & 4095;
    const float* p = ws + GP_OFF + (((size_t)b << 7) << 12) + e;
    float a = 0.f;
#pragma unroll 8
    for (int k = 0; k < 128; ++k) a += p[(size_t)k << 12];
    ws[G_OFF + idx] = a;
  } else {
    const int b = g - 64;
    if (tid < 128) {
      const float* p = ws + SP_OFF + ((b << 7) << 7) + tid;
      float a = 0.f;
#pragma unroll 8
      for (int k = 0; k < 128; ++k) a += p[k << 7];
      if (tid < 64) ws[S1_OFF + (b << 6) + tid] = a;
      else          ws[S2_OFF + (b << 6) + (tid - 64)] = a;
    }
  }
}

// ---------------------------------------------------------------------------
// 64x64 fp32 matmul in swizzled LDS. D[c][d] = sum_k A[c][k] * (TRANSB ? B[d][k] : B[k][d])
template <bool TRANSB>
__device__ __forceinline__ void mm64(const float* __restrict__ A, const float* __restrict__ B,
                                     float* __restrict__ D, int tid) {
  const int c0 = (tid >> 4) << 2;
  const int d0 = (tid & 15) << 2;
  float acc[4][4] = {{0.f}};
#pragma unroll
  for (int kb = 0; kb < 64; kb += 4) {
    float4 a[4];
#pragma unroll
    for (int i = 0; i < 4; ++i) a[i] = ldswz4f(A, c0 + i, kb);
    if (TRANSB) {
#pragma unroll
      for (int j = 0; j < 4; ++j) {
        const float4 bj = ldswz4f(B, d0 + j, kb);
#pragma unroll
        for (int i = 0; i < 4; ++i) {
          acc[i][j] += a[i].x * bj.x + a[i].y * bj.y + a[i].z * bj.z + a[i].w * bj.w;
        }
      }
    } else {
#pragma unroll
      for (int r = 0; r < 4; ++r) {
        const float4 q = ldswz4f(B, kb + r, d0);
        const float br[4] = {q.x, q.y, q.z, q.w};
#pragma unroll
        for (int i = 0; i < 4; ++i) {
          const float av = (r == 0) ? a[i].x : (r == 1) ? a[i].y : (r == 2) ? a[i].z : a[i].w;
#pragma unroll
          for (int j = 0; j < 4; ++j) acc[i][j] += av * br[j];
        }
      }
    }
  }
#pragma unroll
  for (int i = 0; i < 4; ++i) {
    stswz4f(D, c0 + i, d0, make_float4(acc[i][0], acc[i][1], acc[i][2], acc[i][3]));
  }
}

// M = A @ B (non-trans), stored TRANSPOSED to global: Mt[j][o] = M[o][j]
__device__ __forceinline__ void mm64_storeT(const float* __restrict__ A, const float* __restrict__ B,
                                            float* __restrict__ Mt, int tid) {
  const int c0 = (tid >> 4) << 2;
  const int d0 = (tid & 15) << 2;
  float acc[4][4] = {{0.f}};
#pragma unroll
  for (int kb = 0; kb < 64; kb += 4) {
    float4 a[4];
#pragma unroll
    for (int i = 0; i < 4; ++i) a[i] = ldswz4f(A, c0 + i, kb);
#pragma unroll
    for (int r = 0; r < 4; ++r) {
      const float4 q = ldswz4f(B, kb + r, d0);
      const float br[4] = {q.x, q.y, q.z, q.w};
#pragma unroll
      for (int i = 0; i < 4; ++i) {
        const float av = (r == 0) ? a[i].x : (r == 1) ? a[i].y : (r == 2) ? a[i].z : a[i].w;
#pragma unroll
        for (int j = 0; j < 4; ++j) acc[i][j] += av * br[j];
      }
    }
  }
#pragma unroll
  for (int i = 0; i < 4; ++i) {
#pragma unroll
    for (int j = 0; j < 4; ++j) {
      Mt[((d0 + j) << 6) + c0 + i] = acc[i][j];
    }
  }
}

__device__ __forceinline__ void load64x64(const float* __restrict__ g, float* __restrict__ lds, int tid) {
#pragma unroll
  for (int r = 0; r < 4; ++r) {
    const int idx = (r << 8) + tid;
    const int row = idx >> 4;
    const int b4 = (idx & 15) << 2;
    stswz4f(lds, row, b4, *(const float4*)(g + (row << 6) + b4));
  }
}

// ---------------------------------------------------------------------------
// Middle kernel: 8 blocks = 4 batches x 2 sides. Builds logits from G/s,
// softmax, then M (transposed) and c vectors into ws.
__global__ __launch_bounds__(256) void k_mid(
    const float* __restrict__ wq1, const float* __restrict__ bq1,
    const float* __restrict__ wk2, const float* __restrict__ bk2,
    const float* __restrict__ wv2, const float* __restrict__ bv2,
    const float* __restrict__ wo1, const float* __restrict__ bo1,
    const float* __restrict__ wq2, const float* __restrict__ bq2,
    const float* __restrict__ wk1, const float* __restrict__ bk1,
    const float* __restrict__ wv1, const float* __restrict__ bv1,
    const float* __restrict__ wo2, const float* __restrict__ bo2,
    float* __restrict__ ws) {
  __shared__ __align__(16) float LA[4096];
  __shared__ __align__(16) float LB[4096];
  __shared__ __align__(16) float LC[4096];
  __shared__ __align__(16) float LD[4096];
  __shared__ float vsq[64], vsk[64], vaq[64], vkk[64], vcv[64];

  const int tid = threadIdx.x;
  const int b = blockIdx.x >> 1;
  const int side = blockIdx.x & 1;

  const float *Wq, *Bq, *Wk, *Bk, *Wv, *Bv, *Wo, *Bo, *sqp, *skp;
  if (side == 0) {
    Wq = wq1; Bq = bq1; Wk = wk2; Bk = bk2; Wv = wv2; Bv = bv2; Wo = wo1; Bo = bo1;
    sqp = ws + S1_OFF + (b << 6); skp = ws + S2_OFF + (b << 6);
  } else {
    Wq = wq2; Bq = bq2; Wk = wk1; Bk = bk1; Wv = wv1; Bv = bv1; Wo = wo2; Bo = bo2;
    sqp = ws + S2_OFF + (b << 6); skp = ws + S1_OFF + (b << 6);
  }
  float* Mt = ws + MT_OFF + (((side << 2) + b) << 12);
  float* Cv = ws + CV_OFF + (((side << 2) + b) << 6);
  const float* G = ws + G_OFF + (b << 12);

  if (tid < 64) { vsq[tid] = sqp[tid]; vsk[tid] = skp[tid]; }
  load64x64(G, LA, tid);
  load64x64(Wq, LB, tid);
  __syncthreads();
  if (tid < 64) {  // aq = Wq @ sq
    float a = 0.f;
    for (int k = 0; k < 64; ++k) a += ldswz1(LB, tid, k) * vsq[k];
    vaq[tid] = a;
  }
  // T = Wq @ G (side0)  or  Wq @ G^T (side1)
  if (side == 0) mm64<false>(LB, LA, LC, tid);
  else           mm64<true >(LB, LA, LC, tid);
  __syncthreads();
  load64x64(Wk, LB, tid);
  __syncthreads();
  if (tid < 64) {  // kk = Wk @ sk
    float a = 0.f;
    for (int k = 0; k < 64; ++k) a += ldswz1(LB, tid, k) * vsk[k];
    vkk[tid] = a;
  }
  mm64<true>(LC, LB, LD, tid);  // S = T @ Wk^T
  __syncthreads();
  // assemble logits: S = scale*(S + aq[c]*bk[d] + bq[c]*(kk[d] + N*bk[d]))
#pragma unroll
  for (int t = 0; t < 16; ++t) {
    const int idx = (t << 8) + tid;
    const int c = idx >> 6, d = idx & 63;
    const float bkv = Bk[d], bqv = Bq[c];
    float v = ldswz1(LD, c, d);
    v = SCALE * (v + vaq[c] * bkv + bqv * (vkk[d] + 65536.f * bkv));
    stswz1(LD, c, d, v);
  }
  __syncthreads();
  {  // row softmax, 4 lanes per row
    const int row = tid >> 2, q = tid & 3;
    float ev[16];
    float mx = -3.4e38f;
#pragma unroll
    for (int t = 0; t < 16; ++t) { ev[t] = ldswz1(LD, row, q + (t << 2)); mx = fmaxf(mx, ev[t]); }
    mx = fmaxf(mx, __shfl_xor(mx, 1));
    mx = fmaxf(mx, __shfl_xor(mx, 2));
    float sm = 0.f;
#pragma unroll
    for (int t = 0; t < 16; ++t) { ev[t] = __expf(ev[t] - mx); sm += ev[t]; }
    sm += __shfl_xor(sm, 1);
    sm += __shfl_xor(sm, 2);
    const float inv = 1.f / sm;
#pragma unroll
    for (int t = 0; t < 16; ++t) stswz1(LD, row, q + (t << 2), ev[t] * inv);
  }
  __syncthreads();
  if (tid < 64) {  // cv = attn @ bv
    float a = 0.f;
    for (int d = 0; d < 64; ++d) a += ldswz1(LD, tid, d) * Bv[d];
    vcv[tid] = a;
  }
  load64x64(Wv, LB, tid);
  __syncthreads();
  mm64<false>(LD, LB, LC, tid);  // U = attn @ Wv
  __syncthreads();
  load64x64(Wo, LB, tid);
  __syncthreads();
  mm64_storeT(LB, LC, Mt, tid);  // Mt[j][o] = (Wo @ U)[o][j]
  if (tid < 64) {                // c = Wo @ cv + bo
    float a = 0.f;
    for (int c = 0; c < 64; ++c) a += ldswz1(LB, tid, c) * vcv[c];
    Cv[tid] = a + Bo[tid];
  }
}

// ---------------------------------------------------------------------------
// Apply kernel: 512 thr / 8 waves / 64 px per block. Stage X1,X2 tiles
// (32KB LDS, plain [ch][px] layout -> stride-1 lane reads, 2-way free).
// Wave w: side = w>>2, out-channel chunk oc = (w&3)*16 -- wave-uniform, so
// M rows and C are scalar loads. acc[16] per thread; residual from LDS.
__global__ __launch_bounds__(512) void k_apply(const float* __restrict__ x1,
                                               const float* __restrict__ x2,
                                               const float* __restrict__ ws,
                                               float* __restrict__ out) {
  __shared__ __align__(16) float X1s[4096];  // [ch][px] 64x64
  __shared__ __align__(16) float X2s[4096];
  const int tid = threadIdx.x;
  const int b = blockIdx.x >> 10;
  const size_t ib = ((size_t)b << 22) + ((blockIdx.x & 1023) << 6);

  {  // stage both tiles: threads 0-255 -> X1, 256-511 -> X2 (wave-aligned)
    const float* src = (tid < 256) ? x1 : x2;
    float* dst = (tid < 256) ? X1s : X2s;
    const int tt = tid & 255;
    const int row = tt >> 2;                 // channel
    const int f4 = (tt & 3) << 2;            // float4 index 0,4,8,12
    const float4* g = (const float4*)(src + ib + ((size_t)row << 16)) + f4;
    float4* d = (float4*)(dst + (row << 6)) + f4;
#pragma unroll
    for (int q = 0; q < 4; ++q) d[q] = g[q];
  }
  __syncthreads();

  const int wu = __builtin_amdgcn_readfirstlane(tid >> 6);  // wave id, SGPR
  const int side = wu >> 2;
  const int oc = (wu & 3) << 4;
  const int lane = tid & 63;
  const int job = (side << 2) + b;
  const float* Mt = ws + MT_OFF + ((size_t)job << 12);  // Mt[j][o]
  const float* Cv = ws + CV_OFF + (job << 6);
  const float* Xown = side == 0 ? X1s : X2s;
  const float* Xoth = side == 0 ? X2s : X1s;

  float acc[16];
#pragma unroll
  for (int oi = 0; oi < 16; ++oi) {
    acc[oi] = Cv[oc + oi] + Xown[((oc + oi) << 6) + lane];  // c + residual
  }

#pragma unroll
  for (int j = 0; j < 64; ++j) {
    const float xv = Xoth[(j << 6) + lane];
    const float* mrow = Mt + (j << 6) + oc;   // uniform -> s_load
#pragma unroll
    for (int oi = 0; oi < 16; ++oi) acc[oi] += mrow[oi] * xv;
  }

  float* o = out + ((size_t)side << 24) + ib + ((size_t)oc << 16) + lane;
#pragma unroll
  for (int oi = 0; oi < 16; ++oi) o[(size_t)oi << 16] = acc[oi];
}

// ---------------------------------------------------------------------------
extern "C" void kernel_launch(void* const* d_in, const int* in_sizes, int n_in,
                              void* d_out, int out_size, void* d_ws, size_t ws_size,
                              hipStream_t stream) {
  const float* x1 = (const float*)d_in[0];
  const float* x2 = (const float*)d_in[1];
  float* ws = (float*)d_ws;
  float* out = (float*)d_out;

  k_gram<<<NBLK_GRAM, 256, 0, stream>>>(x1, x2, ws + GP_OFF, ws + SP_OFF);
  k_reduce<<<68, 256, 0, stream>>>(ws);
  k_mid<<<8, 256, 0, stream>>>(
      (const float*)d_in[2],  (const float*)d_in[3],   // w_q1, b_q1
      (const float*)d_in[4],  (const float*)d_in[5],   // w_k2, b_k2
      (const float*)d_in[6],  (const float*)d_in[7],   // w_v2, b_v2
      (const float*)d_in[14], (const float*)d_in[15],  // w_o1, b_o1
      (const float*)d_in[8],  (const float*)d_in[9],   // w_q2, b_q2
      (const float*)d_in[10], (const float*)d_in[11],  // w_k1, b_k1
      (const float*)d_in[12], (const float*)d_in[13],  // w_v1, b_v1
      (const float*)d_in[16], (const float*)d_in[17],  // w_o2, b_o2
      ws);
  k_apply<<<4096, 512, 0, stream>>>(x1, x2, ws, out);
}

// Round 5
// 140.350 us; speedup vs baseline: 7.5335x; 5.9068x over previous
//
#include <hip/hip_runtime.h>

// ---------------------------------------------------------------------------
// SymmetricCrossAttention, B=4, C=64, H=W=256, HEADS=1.
// out1 = M1 X2 + c1 + X1, out2 = M2 X1 + c2 + X2 with M,c derived from
// G12 = X1 X2^T (64x64 per batch) + channel sums (k_gram/k_reduce/k_mid).
// R5: k_gram rewritten on MFMA (bf16 hi/lo split, 3 mfma per tile = fp32-
//     accurate). acc = 16 AGPR/lane (was 64 VGPR) -> no spill, no
//     launch_bounds fight. global_load_lds(16B) staging, linear LDS dst +
//     pre-swizzled global src (m173), XOR-swizzled reads (<=2-way).
// ---------------------------------------------------------------------------

#define NPIX 65536
#define SCALE 0.125f
#define NBLK_GRAM 512      // 4 batches * 128 chunks (512 px each)

// workspace float offsets
#define GP_OFF  0                      // 512 * 4096 partial Grams
#define SP_OFF  2097152                // 512 * 128 partial channel sums (s1|s2)
#define G_OFF   2162688                // 4 * 4096
#define S1_OFF  2179072                // 4 * 64
#define S2_OFF  2179328                // 4 * 64
#define MT_OFF  2179584                // 2*4*4096, M stored transposed Mt[j][o]
#define CV_OFF  2212352                // 2*4*64
#define WS_FLOATS 2212864              // ~8.85 MB

typedef __attribute__((ext_vector_type(8))) short bf16x8;  // 4 VGPR A/B frag
typedef __attribute__((ext_vector_type(4))) float f32x4;   // 16x16 C/D frag

// ---- XOR-swizzled 64x64 fp32 LDS tile helpers (16B-block index ^ (row>>2)&7)
__device__ __forceinline__ int swzidx(int row, int k) {
  return (row << 6) + ((((k >> 2) ^ ((row >> 2) & 7)) << 2) | (k & 3));
}
__device__ __forceinline__ float ldswz1(const float* b, int row, int k) {
  return b[swzidx(row, k)];
}
__device__ __forceinline__ void stswz1(float* b, int row, int k, float v) {
  b[swzidx(row, k)] = v;
}
__device__ __forceinline__ float4 ldswz4f(const float* b, int row, int k) { // k%4==0
  return *(const float4*)(b + (row << 6) + ((((k >> 2) ^ ((row >> 2) & 7)) << 2)));
}
__device__ __forceinline__ void stswz4f(float* b, int row, int k, float4 v) {
  *(float4*)(b + (row << 6) + ((((k >> 2) ^ ((row >> 2) & 7)) << 2))) = v;
}

// ---- async global->LDS 16B (wave-uniform LDS base + lane*16; global per-lane)
__device__ __forceinline__ void gload_lds16(const float* g, float* l) {
  __builtin_amdgcn_global_load_lds(
      (const __attribute__((address_space(1))) unsigned int*)g,
      (__attribute__((address_space(3))) unsigned int*)l, 16, 0, 0);
}

// ---- fp32 -> bf16 hi/lo split (truncation; lo captures next 16 mantissa bits)
__device__ __forceinline__ void cvt_hilo(float4 p, float4 q, bf16x8& hi, bf16x8& lo) {
  float x[8] = {p.x, p.y, p.z, p.w, q.x, q.y, q.z, q.w};
#pragma unroll
  for (int j = 0; j < 8; ++j) {
    const unsigned u = __float_as_uint(x[j]);
    const float hf = __uint_as_float(u & 0xFFFF0000u);
    hi[j] = (short)(u >> 16);
    lo[j] = (short)(__float_as_uint(x[j] - hf) >> 16);
  }
}

// ---------------------------------------------------------------------------
// Gram kernel (MFMA): per batch, G12 = X1 X2^T (64x64) + channel sums.
// 512 blocks = 4 batches * 128 chunks; chunk = 512 px = 8 tiles of 64 px.
// LDS: X[64ch][16 px-blocks], linear dst for global_load_lds; global source
// pre-swizzled so that LDS block kb holds px-block kb^(c&7).
// Wave w owns G rows 16w..16w+15: 4 col-tiles, acc 16 f32/lane, full k.
__global__ __launch_bounds__(256) void k_gram(const float* __restrict__ x1,
                                              const float* __restrict__ x2,
                                              float* __restrict__ gp,
                                              float* __restrict__ sp) {
  __shared__ __align__(16) float X1s[4096];
  __shared__ __align__(16) float X2s[4096];
  const int tid = threadIdx.x;
  const int b = blockIdx.x >> 7;
  const int chunk = blockIdx.x & 127;
  const size_t base = ((size_t)b << 22) + ((size_t)chunk << 9);

  const int w = tid >> 6;          // wave id -> G row-block
  const int l = tid & 63;
  const int lrow = l & 15;         // A row / B col within 16
  const int lkg = l >> 4;          // k-group (8 px each)
  const int arow = (w << 4) + lrow;

  f32x4 acc[4] = {};               // 4 col-tiles of wave's 16x64 G strip
  float s_own = 0.f;               // channel-sum piece (half a row per thread)
  const int srow128 = tid >> 1;    // 0..127: 0-63 -> X1 ch, 64-127 -> X2 ch
  const int sr = srow128 & 63;
  const float* sarr = (srow128 < 64) ? X1s : X2s;
  const int shalf = (tid & 1) << 3;

  for (int t = 0; t < 8; ++t) {
    __syncthreads();  // previous tile fully consumed
    // stage: wave w stages 1KB chunks 4w..4w+3 of each array
#pragma unroll
    for (int q = 0; q < 4; ++q) {
      const int ck = (w << 2) + q;              // 1KB chunk 0..15
      const int c = (ck << 2) + lkg;            // channel row
      const int kb = lrow;                      // LDS px-block this lane fills
      const size_t off = base + ((size_t)c << 16) + (t << 6) + ((kb ^ (c & 7)) << 2);
      gload_lds16(x1 + off, &X1s[ck << 8]);
      gload_lds16(x2 + off, &X2s[ck << 8]);
    }
    __syncthreads();  // vmcnt drained by barrier -> tile ready

    // channel sums (any block order works; XOR spreads banks)
#pragma unroll
    for (int j = 0; j < 8; ++j) {
      const int kb2 = (shalf + j) ^ (sr & 7);
      const float4 v = *(const float4*)&sarr[(sr << 6) + (kb2 << 2)];
      s_own += v.x + v.y + v.z + v.w;
    }

    // MFMA: 2 k-steps of 32 px
#pragma unroll
    for (int ks = 0; ks < 2; ++ks) {
      const int kb0 = (ks << 3) + (lkg << 1);   // desired px-block pair
      bf16x8 ahi, alo;
      {
        const float4 p = *(const float4*)&X1s[(arow << 6) + ((kb0 ^ (arow & 7)) << 2)];
        const float4 q2 = *(const float4*)&X1s[(arow << 6) + (((kb0 + 1) ^ (arow & 7)) << 2)];
        cvt_hilo(p, q2, ahi, alo);
      }
#pragma unroll
      for (int n = 0; n < 4; ++n) {
        const int brow = (n << 4) + lrow;
        const float4 p = *(const float4*)&X2s[(brow << 6) + ((kb0 ^ (brow & 7)) << 2)];
        const float4 q2 = *(const float4*)&X2s[(brow << 6) + (((kb0 + 1) ^ (brow & 7)) << 2)];
        bf16x8 bhi, blo;
        cvt_hilo(p, q2, bhi, blo);
        acc[n] = __builtin_amdgcn_mfma_f32_16x16x32_bf16(ahi, bhi, acc[n], 0, 0, 0);
        acc[n] = __builtin_amdgcn_mfma_f32_16x16x32_bf16(ahi, blo, acc[n], 0, 0, 0);
        acc[n] = __builtin_amdgcn_mfma_f32_16x16x32_bf16(alo, bhi, acc[n], 0, 0, 0);
      }
    }
  }

  // channel-sum partials: pair-reduce adjacent lanes, one write per row
  {
    const float so = s_own + __shfl_xor(s_own, 1);
    if ((tid & 1) == 0) sp[(blockIdx.x << 7) + srow128] = so;
  }
  // G partial: C/D layout col=lane&15, row=(lane>>4)*4+reg (m89-verified)
  float* g = gp + ((size_t)blockIdx.x << 12);
#pragma unroll
  for (int n = 0; n < 4; ++n) {
#pragma unroll
    for (int r = 0; r < 4; ++r) {
      g[(((w << 4) + (lkg << 2) + r) << 6) + (n << 4) + lrow] = acc[n][r];
    }
  }
}

// ---------------------------------------------------------------------------
// Reduce 128 partials per batch into final G and channel sums.
__global__ __launch_bounds__(256) void k_reduce(float* __restrict__ ws) {
  const int g = blockIdx.x;
  const int tid = threadIdx.x;
  if (g < 64) {
    const int idx = (g << 8) + tid;            // 0..16383
    const int b = idx >> 12, e = idx & 4095;
    const float* p = ws + GP_OFF + (((size_t)b << 7) << 12) + e;
    float a = 0.f;
#pragma unroll 8
    for (int k = 0; k < 128; ++k) a += p[(size_t)k << 12];
    ws[G_OFF + idx] = a;
  } else {
    const int b = g - 64;
    if (tid < 128) {
      const float* p = ws + SP_OFF + ((b << 7) << 7) + tid;
      float a = 0.f;
#pragma unroll 8
      for (int k = 0; k < 128; ++k) a += p[k << 7];
      if (tid < 64) ws[S1_OFF + (b << 6) + tid] = a;
      else          ws[S2_OFF + (b << 6) + (tid - 64)] = a;
    }
  }
}

// ---------------------------------------------------------------------------
// 64x64 fp32 matmul in swizzled LDS. D[c][d] = sum_k A[c][k] * (TRANSB ? B[d][k] : B[k][d])
template <bool TRANSB>
__device__ __forceinline__ void mm64(const float* __restrict__ A, const float* __restrict__ B,
                                     float* __restrict__ D, int tid) {
  const int c0 = (tid >> 4) << 2;
  const int d0 = (tid & 15) << 2;
  float acc[4][4] = {{0.f}};
#pragma unroll
  for (int kb = 0; kb < 64; kb += 4) {
    float4 a[4];
#pragma unroll
    for (int i = 0; i < 4; ++i) a[i] = ldswz4f(A, c0 + i, kb);
    if (TRANSB) {
#pragma unroll
      for (int j = 0; j < 4; ++j) {
        const float4 bj = ldswz4f(B, d0 + j, kb);
#pragma unroll
        for (int i = 0; i < 4; ++i) {
          acc[i][j] += a[i].x * bj.x + a[i].y * bj.y + a[i].z * bj.z + a[i].w * bj.w;
        }
      }
    } else {
#pragma unroll
      for (int r = 0; r < 4; ++r) {
        const float4 q = ldswz4f(B, kb + r, d0);
        const float br[4] = {q.x, q.y, q.z, q.w};
#pragma unroll
        for (int i = 0; i < 4; ++i) {
          const float av = (r == 0) ? a[i].x : (r == 1) ? a[i].y : (r == 2) ? a[i].z : a[i].w;
#pragma unroll
          for (int j = 0; j < 4; ++j) acc[i][j] += av * br[j];
        }
      }
    }
  }
#pragma unroll
  for (int i = 0; i < 4; ++i) {
    stswz4f(D, c0 + i, d0, make_float4(acc[i][0], acc[i][1], acc[i][2], acc[i][3]));
  }
}

// M = A @ B (non-trans), stored TRANSPOSED to global: Mt[j][o] = M[o][j]
__device__ __forceinline__ void mm64_storeT(const float* __restrict__ A, const float* __restrict__ B,
                                            float* __restrict__ Mt, int tid) {
  const int c0 = (tid >> 4) << 2;
  const int d0 = (tid & 15) << 2;
  float acc[4][4] = {{0.f}};
#pragma unroll
  for (int kb = 0; kb < 64; kb += 4) {
    float4 a[4];
#pragma unroll
    for (int i = 0; i < 4; ++i) a[i] = ldswz4f(A, c0 + i, kb);
#pragma unroll
    for (int r = 0; r < 4; ++r) {
      const float4 q = ldswz4f(B, kb + r, d0);
      const float br[4] = {q.x, q.y, q.z, q.w};
#pragma unroll
      for (int i = 0; i < 4; ++i) {
        const float av = (r == 0) ? a[i].x : (r == 1) ? a[i].y : (r == 2) ? a[i].z : a[i].w;
#pragma unroll
        for (int j = 0; j < 4; ++j) acc[i][j] += av * br[j];
      }
    }
  }
#pragma unroll
  for (int i = 0; i < 4; ++i) {
#pragma unroll
    for (int j = 0; j < 4; ++j) {
      Mt[((d0 + j) << 6) + c0 + i] = acc[i][j];
    }
  }
}

__device__ __forceinline__ void load64x64(const float* __restrict__ g, float* __restrict__ lds, int tid) {
#pragma unroll
  for (int r = 0; r < 4; ++r) {
    const int idx = (r << 8) + tid;
    const int row = idx >> 4;
    const int b4 = (idx & 15) << 2;
    stswz4f(lds, row, b4, *(const float4*)(g + (row << 6) + b4));
  }
}

// ---------------------------------------------------------------------------
// Middle kernel: 8 blocks = 4 batches x 2 sides. Builds logits from G/s,
// softmax, then M (transposed) and c vectors into ws.
__global__ __launch_bounds__(256) void k_mid(
    const float* __restrict__ wq1, const float* __restrict__ bq1,
    const float* __restrict__ wk2, const float* __restrict__ bk2,
    const float* __restrict__ wv2, const float* __restrict__ bv2,
    const float* __restrict__ wo1, const float* __restrict__ bo1,
    const float* __restrict__ wq2, const float* __restrict__ bq2,
    const float* __restrict__ wk1, const float* __restrict__ bk1,
    const float* __restrict__ wv1, const float* __restrict__ bv1,
    const float* __restrict__ wo2, const float* __restrict__ bo2,
    float* __restrict__ ws) {
  __shared__ __align__(16) float LA[4096];
  __shared__ __align__(16) float LB[4096];
  __shared__ __align__(16) float LC[4096];
  __shared__ __align__(16) float LD[4096];
  __shared__ float vsq[64], vsk[64], vaq[64], vkk[64], vcv[64];

  const int tid = threadIdx.x;
  const int b = blockIdx.x >> 1;
  const int side = blockIdx.x & 1;

  const float *Wq, *Bq, *Wk, *Bk, *Wv, *Bv, *Wo, *Bo, *sqp, *skp;
  if (side == 0) {
    Wq = wq1; Bq = bq1; Wk = wk2; Bk = bk2; Wv = wv2; Bv = bv2; Wo = wo1; Bo = bo1;
    sqp = ws + S1_OFF + (b << 6); skp = ws + S2_OFF + (b << 6);
  } else {
    Wq = wq2; Bq = bq2; Wk = wk1; Bk = bk1; Wv = wv1; Bv = bv1; Wo = wo2; Bo = bo2;
    sqp = ws + S2_OFF + (b << 6); skp = ws + S1_OFF + (b << 6);
  }
  float* Mt = ws + MT_OFF + (((side << 2) + b) << 12);
  float* Cv = ws + CV_OFF + (((side << 2) + b) << 6);
  const float* G = ws + G_OFF + (b << 12);

  if (tid < 64) { vsq[tid] = sqp[tid]; vsk[tid] = skp[tid]; }
  load64x64(G, LA, tid);
  load64x64(Wq, LB, tid);
  __syncthreads();
  if (tid < 64) {  // aq = Wq @ sq
    float a = 0.f;
    for (int k = 0; k < 64; ++k) a += ldswz1(LB, tid, k) * vsq[k];
    vaq[tid] = a;
  }
  // T = Wq @ G (side0)  or  Wq @ G^T (side1)
  if (side == 0) mm64<false>(LB, LA, LC, tid);
  else           mm64<true >(LB, LA, LC, tid);
  __syncthreads();
  load64x64(Wk, LB, tid);
  __syncthreads();
  if (tid < 64) {  // kk = Wk @ sk
    float a = 0.f;
    for (int k = 0; k < 64; ++k) a += ldswz1(LB, tid, k) * vsk[k];
    vkk[tid] = a;
  }
  mm64<true>(LC, LB, LD, tid);  // S = T @ Wk^T
  __syncthreads();
  // assemble logits: S = scale*(S + aq[c]*bk[d] + bq[c]*(kk[d] + N*bk[d]))
#pragma unroll
  for (int t = 0; t < 16; ++t) {
    const int idx = (t << 8) + tid;
    const int c = idx >> 6, d = idx & 63;
    const float bkv = Bk[d], bqv = Bq[c];
    float v = ldswz1(LD, c, d);
    v = SCALE * (v + vaq[c] * bkv + bqv * (vkk[d] + 65536.f * bkv));
    stswz1(LD, c, d, v);
  }
  __syncthreads();
  {  // row softmax, 4 lanes per row
    const int row = tid >> 2, q = tid & 3;
    float ev[16];
    float mx = -3.4e38f;
#pragma unroll
    for (int t = 0; t < 16; ++t) { ev[t] = ldswz1(LD, row, q + (t << 2)); mx = fmaxf(mx, ev[t]); }
    mx = fmaxf(mx, __shfl_xor(mx, 1));
    mx = fmaxf(mx, __shfl_xor(mx, 2));
    float sm = 0.f;
#pragma unroll
    for (int t = 0; t < 16; ++t) { ev[t] = __expf(ev[t] - mx); sm += ev[t]; }
    sm += __shfl_xor(sm, 1);
    sm += __shfl_xor(sm, 2);
    const float inv = 1.f / sm;
#pragma unroll
    for (int t = 0; t < 16; ++t) stswz1(LD, row, q + (t << 2), ev[t] * inv);
  }
  __syncthreads();
  if (tid < 64) {  // cv = attn @ bv
    float a = 0.f;
    for (int d = 0; d < 64; ++d) a += ldswz1(LD, tid, d) * Bv[d];
    vcv[tid] = a;
  }
  load64x64(Wv, LB, tid);
  __syncthreads();
  mm64<false>(LD, LB, LC, tid);  // U = attn @ Wv
  __syncthreads();
  load64x64(Wo, LB, tid);
  __syncthreads();
  mm64_storeT(LB, LC, Mt, tid);  // Mt[j][o] = (Wo @ U)[o][j]
  if (tid < 64) {                // c = Wo @ cv + bo
    float a = 0.f;
    for (int c = 0; c < 64; ++c) a += ldswz1(LB, tid, c) * vcv[c];
    Cv[tid] = a + Bo[tid];
  }
}

// ---------------------------------------------------------------------------
// Apply kernel: 512 thr / 8 waves / 64 px per block. Stage X1,X2 tiles
// (32KB LDS, plain [ch][px] layout -> stride-1 lane reads, 2-way free).
// Wave w: side = w>>2, out-channel chunk oc = (w&3)*16 -- wave-uniform, so
// M rows and C are scalar loads. acc[16] per thread; residual from LDS.
__global__ __launch_bounds__(512) void k_apply(const float* __restrict__ x1,
                                               const float* __restrict__ x2,
                                               const float* __restrict__ ws,
                                               float* __restrict__ out) {
  __shared__ __align__(16) float X1s[4096];  // [ch][px] 64x64
  __shared__ __align__(16) float X2s[4096];
  const int tid = threadIdx.x;
  const int b = blockIdx.x >> 10;
  const size_t ib = ((size_t)b << 22) + ((blockIdx.x & 1023) << 6);

  {  // stage both tiles: threads 0-255 -> X1, 256-511 -> X2 (wave-aligned)
    const float* src = (tid < 256) ? x1 : x2;
    float* dst = (tid < 256) ? X1s : X2s;
    const int tt = tid & 255;
    const int row = tt >> 2;                 // channel
    const int f4 = (tt & 3) << 2;            // float4 index 0,4,8,12
    const float4* g = (const float4*)(src + ib + ((size_t)row << 16)) + f4;
    float4* d = (float4*)(dst + (row << 6)) + f4;
#pragma unroll
    for (int q = 0; q < 4; ++q) d[q] = g[q];
  }
  __syncthreads();

  const int wu = __builtin_amdgcn_readfirstlane(tid >> 6);  // wave id, SGPR
  const int side = wu >> 2;
  const int oc = (wu & 3) << 4;
  const int lane = tid & 63;
  const int job = (side << 2) + b;
  const float* Mt = ws + MT_OFF + ((size_t)job << 12);  // Mt[j][o]
  const float* Cv = ws + CV_OFF + (job << 6);
  const float* Xown = side == 0 ? X1s : X2s;
  const float* Xoth = side == 0 ? X2s : X1s;

  float acc[16];
#pragma unroll
  for (int oi = 0; oi < 16; ++oi) {
    acc[oi] = Cv[oc + oi] + Xown[((oc + oi) << 6) + lane];  // c + residual
  }

#pragma unroll
  for (int j = 0; j < 64; ++j) {
    const float xv = Xoth[(j << 6) + lane];
    const float* mrow = Mt + (j << 6) + oc;   // uniform -> s_load
#pragma unroll
    for (int oi = 0; oi < 16; ++oi) acc[oi] += mrow[oi] * xv;
  }

  float* o = out + ((size_t)side << 24) + ib + ((size_t)oc << 16) + lane;
#pragma unroll
  for (int oi = 0; oi < 16; ++oi) o[(size_t)oi << 16] = acc[oi];
}

// ---------------------------------------------------------------------------
extern "C" void kernel_launch(void* const* d_in, const int* in_sizes, int n_in,
                              void* d_out, int out_size, void* d_ws, size_t ws_size,
                              hipStream_t stream) {
  const float* x1 = (const float*)d_in[0];
  const float* x2 = (const float*)d_in[1];
  float* ws = (float*)d_ws;
  float* out = (float*)d_out;

  k_gram<<<NBLK_GRAM, 256, 0, stream>>>(x1, x2, ws + GP_OFF, ws + SP_OFF);
  k_reduce<<<68, 256, 0, stream>>>(ws);
  k_mid<<<8, 256, 0, stream>>>(
      (const float*)d_in[2],  (const float*)d_in[3],   // w_q1, b_q1
      (const float*)d_in[4],  (const float*)d_in[5],   // w_k2, b_k2
      (const float*)d_in[6],  (const float*)d_in[7],   // w_v2, b_v2
      (const float*)d_in[14], (const float*)d_in[15],  // w_o1, b_o1
      (const float*)d_in[8],  (const float*)d_in[9],   // w_q2, b_q2
      (const float*)d_in[10], (const float*)d_in[11],  // w_k1, b_k1
      (const float*)d_in[12], (const float*)d_in[13],  // w_v1, b_v1
      (const float*)d_in[16], (const float*)d_in[17],  // w_o2, b_o2
      ws);
  k_apply<<<4096, 512, 0, stream>>>(x1, x2, ws, out);
}

// Round 6
// 132.444 us; speedup vs baseline: 7.9832x; 1.0597x over previous
//
#include <hip/hip_runtime.h>

// ---------------------------------------------------------------------------
// SymmetricCrossAttention, B=4, C=64, H=W=256, HEADS=1.
// out1 = M1 X2 + c1 + X1, out2 = M2 X1 + c2 + X2 with M,c derived from
// G12 = X1 X2^T (64x64 per batch) + channel sums (k_gram/k_reduce/k_mid).
// R6: k_apply restructured: 128-px tiles, both sides in 64KB LDS via
//     global_load_lds(16B) (no VALU staging), lane owns a px-pair ->
//     inner loop = 1 ds_read_b64 + s_load_dwordx4 x4 (M row, uniform) +
//     32 FMA; acc[16][2]=32 VGPR. Was: b32 reads + 16 scalar s_loads/j,
//     4096 blocks, 90us at 63% VALUBusy.
// ---------------------------------------------------------------------------

#define NPIX 65536
#define SCALE 0.125f
#define NBLK_GRAM 512      // 4 batches * 128 chunks (512 px each)

// workspace float offsets
#define GP_OFF  0                      // 512 * 4096 partial Grams
#define SP_OFF  2097152                // 512 * 128 partial channel sums (s1|s2)
#define G_OFF   2162688                // 4 * 4096
#define S1_OFF  2179072                // 4 * 64
#define S2_OFF  2179328                // 4 * 64
#define MT_OFF  2179584                // 2*4*4096, M stored transposed Mt[j][o]
#define CV_OFF  2212352                // 2*4*64
#define WS_FLOATS 2212864              // ~8.85 MB

typedef __attribute__((ext_vector_type(8))) short bf16x8;  // 4 VGPR A/B frag
typedef __attribute__((ext_vector_type(4))) float f32x4;   // 16x16 C/D frag

// ---- XOR-swizzled 64x64 fp32 LDS tile helpers (16B-block index ^ (row>>2)&7)
__device__ __forceinline__ int swzidx(int row, int k) {
  return (row << 6) + ((((k >> 2) ^ ((row >> 2) & 7)) << 2) | (k & 3));
}
__device__ __forceinline__ float ldswz1(const float* b, int row, int k) {
  return b[swzidx(row, k)];
}
__device__ __forceinline__ void stswz1(float* b, int row, int k, float v) {
  b[swzidx(row, k)] = v;
}
__device__ __forceinline__ float4 ldswz4f(const float* b, int row, int k) { // k%4==0
  return *(const float4*)(b + (row << 6) + ((((k >> 2) ^ ((row >> 2) & 7)) << 2)));
}
__device__ __forceinline__ void stswz4f(float* b, int row, int k, float4 v) {
  *(float4*)(b + (row << 6) + ((((k >> 2) ^ ((row >> 2) & 7)) << 2))) = v;
}

// ---- async global->LDS 16B (wave-uniform LDS base + lane*16; global per-lane)
__device__ __forceinline__ void gload_lds16(const float* g, float* l) {
  __builtin_amdgcn_global_load_lds(
      (const __attribute__((address_space(1))) unsigned int*)g,
      (__attribute__((address_space(3))) unsigned int*)l, 16, 0, 0);
}

// ---- fp32 -> bf16 hi/lo split (truncation; lo captures next 16 mantissa bits)
__device__ __forceinline__ void cvt_hilo(float4 p, float4 q, bf16x8& hi, bf16x8& lo) {
  float x[8] = {p.x, p.y, p.z, p.w, q.x, q.y, q.z, q.w};
#pragma unroll
  for (int j = 0; j < 8; ++j) {
    const unsigned u = __float_as_uint(x[j]);
    const float hf = __uint_as_float(u & 0xFFFF0000u);
    hi[j] = (short)(u >> 16);
    lo[j] = (short)(__float_as_uint(x[j] - hf) >> 16);
  }
}

// ---------------------------------------------------------------------------
// Gram kernel (MFMA): per batch, G12 = X1 X2^T (64x64) + channel sums.
// 512 blocks = 4 batches * 128 chunks; chunk = 512 px = 8 tiles of 64 px.
// LDS: X[64ch][16 px-blocks], linear dst for global_load_lds; global source
// pre-swizzled so that LDS block kb holds px-block kb^(c&7).
// Wave w owns G rows 16w..16w+15: 4 col-tiles, acc 16 f32/lane, full k.
__global__ __launch_bounds__(256) void k_gram(const float* __restrict__ x1,
                                              const float* __restrict__ x2,
                                              float* __restrict__ gp,
                                              float* __restrict__ sp) {
  __shared__ __align__(16) float X1s[4096];
  __shared__ __align__(16) float X2s[4096];
  const int tid = threadIdx.x;
  const int b = blockIdx.x >> 7;
  const int chunk = blockIdx.x & 127;
  const size_t base = ((size_t)b << 22) + ((size_t)chunk << 9);

  const int w = tid >> 6;          // wave id -> G row-block
  const int l = tid & 63;
  const int lrow = l & 15;         // A row / B col within 16
  const int lkg = l >> 4;          // k-group (8 px each)
  const int arow = (w << 4) + lrow;

  f32x4 acc[4] = {};               // 4 col-tiles of wave's 16x64 G strip
  float s_own = 0.f;               // channel-sum piece (half a row per thread)
  const int srow128 = tid >> 1;    // 0..127: 0-63 -> X1 ch, 64-127 -> X2 ch
  const int sr = srow128 & 63;
  const float* sarr = (srow128 < 64) ? X1s : X2s;
  const int shalf = (tid & 1) << 3;

  for (int t = 0; t < 8; ++t) {
    __syncthreads();  // previous tile fully consumed
    // stage: wave w stages 1KB chunks 4w..4w+3 of each array
#pragma unroll
    for (int q = 0; q < 4; ++q) {
      const int ck = (w << 2) + q;              // 1KB chunk 0..15
      const int c = (ck << 2) + lkg;            // channel row
      const int kb = lrow;                      // LDS px-block this lane fills
      const size_t off = base + ((size_t)c << 16) + (t << 6) + ((kb ^ (c & 7)) << 2);
      gload_lds16(x1 + off, &X1s[ck << 8]);
      gload_lds16(x2 + off, &X2s[ck << 8]);
    }
    __syncthreads();  // vmcnt drained by barrier -> tile ready

    // channel sums (any block order works; XOR spreads banks)
#pragma unroll
    for (int j = 0; j < 8; ++j) {
      const int kb2 = (shalf + j) ^ (sr & 7);
      const float4 v = *(const float4*)&sarr[(sr << 6) + (kb2 << 2)];
      s_own += v.x + v.y + v.z + v.w;
    }

    // MFMA: 2 k-steps of 32 px
#pragma unroll
    for (int ks = 0; ks < 2; ++ks) {
      const int kb0 = (ks << 3) + (lkg << 1);   // desired px-block pair
      bf16x8 ahi, alo;
      {
        const float4 p = *(const float4*)&X1s[(arow << 6) + ((kb0 ^ (arow & 7)) << 2)];
        const float4 q2 = *(const float4*)&X1s[(arow << 6) + (((kb0 + 1) ^ (arow & 7)) << 2)];
        cvt_hilo(p, q2, ahi, alo);
      }
#pragma unroll
      for (int n = 0; n < 4; ++n) {
        const int brow = (n << 4) + lrow;
        const float4 p = *(const float4*)&X2s[(brow << 6) + ((kb0 ^ (brow & 7)) << 2)];
        const float4 q2 = *(const float4*)&X2s[(brow << 6) + (((kb0 + 1) ^ (brow & 7)) << 2)];
        bf16x8 bhi, blo;
        cvt_hilo(p, q2, bhi, blo);
        acc[n] = __builtin_amdgcn_mfma_f32_16x16x32_bf16(ahi, bhi, acc[n], 0, 0, 0);
        acc[n] = __builtin_amdgcn_mfma_f32_16x16x32_bf16(ahi, blo, acc[n], 0, 0, 0);
        acc[n] = __builtin_amdgcn_mfma_f32_16x16x32_bf16(alo, bhi, acc[n], 0, 0, 0);
      }
    }
  }

  // channel-sum partials: pair-reduce adjacent lanes, one write per row
  {
    const float so = s_own + __shfl_xor(s_own, 1);
    if ((tid & 1) == 0) sp[(blockIdx.x << 7) + srow128] = so;
  }
  // G partial: C/D layout col=lane&15, row=(lane>>4)*4+reg (m89-verified)
  float* g = gp + ((size_t)blockIdx.x << 12);
#pragma unroll
  for (int n = 0; n < 4; ++n) {
#pragma unroll
    for (int r = 0; r < 4; ++r) {
      g[(((w << 4) + (lkg << 2) + r) << 6) + (n << 4) + lrow] = acc[n][r];
    }
  }
}

// ---------------------------------------------------------------------------
// Reduce 128 partials per batch into final G and channel sums.
__global__ __launch_bounds__(256) void k_reduce(float* __restrict__ ws) {
  const int g = blockIdx.x;
  const int tid = threadIdx.x;
  if (g < 64) {
    const int idx = (g << 8) + tid;            // 0..16383
    const int b = idx >> 12, e = idx & 4095;
    const float* p = ws + GP_OFF + (((size_t)b << 7) << 12) + e;
    float a = 0.f;
#pragma unroll 8
    for (int k = 0; k < 128; ++k) a += p[(size_t)k << 12];
    ws[G_OFF + idx] = a;
  } else {
    const int b = g - 64;
    if (tid < 128) {
      const float* p = ws + SP_OFF + ((b << 7) << 7) + tid;
      float a = 0.f;
#pragma unroll 8
      for (int k = 0; k < 128; ++k) a += p[k << 7];
      if (tid < 64) ws[S1_OFF + (b << 6) + tid] = a;
      else          ws[S2_OFF + (b << 6) + (tid - 64)] = a;
    }
  }
}

// ---------------------------------------------------------------------------
// 64x64 fp32 matmul in swizzled LDS. D[c][d] = sum_k A[c][k] * (TRANSB ? B[d][k] : B[k][d])
template <bool TRANSB>
__device__ __forceinline__ void mm64(const float* __restrict__ A, const float* __restrict__ B,
                                     float* __restrict__ D, int tid) {
  const int c0 = (tid >> 4) << 2;
  const int d0 = (tid & 15) << 2;
  float acc[4][4] = {{0.f}};
#pragma unroll
  for (int kb = 0; kb < 64; kb += 4) {
    float4 a[4];
#pragma unroll
    for (int i = 0; i < 4; ++i) a[i] = ldswz4f(A, c0 + i, kb);
    if (TRANSB) {
#pragma unroll
      for (int j = 0; j < 4; ++j) {
        const float4 bj = ldswz4f(B, d0 + j, kb);
#pragma unroll
        for (int i = 0; i < 4; ++i) {
          acc[i][j] += a[i].x * bj.x + a[i].y * bj.y + a[i].z * bj.z + a[i].w * bj.w;
        }
      }
    } else {
#pragma unroll
      for (int r = 0; r < 4; ++r) {
        const float4 q = ldswz4f(B, kb + r, d0);
        const float br[4] = {q.x, q.y, q.z, q.w};
#pragma unroll
        for (int i = 0; i < 4; ++i) {
          const float av = (r == 0) ? a[i].x : (r == 1) ? a[i].y : (r == 2) ? a[i].z : a[i].w;
#pragma unroll
          for (int j = 0; j < 4; ++j) acc[i][j] += av * br[j];
        }
      }
    }
  }
#pragma unroll
  for (int i = 0; i < 4; ++i) {
    stswz4f(D, c0 + i, d0, make_float4(acc[i][0], acc[i][1], acc[i][2], acc[i][3]));
  }
}

// M = A @ B (non-trans), stored TRANSPOSED to global: Mt[j][o] = M[o][j]
__device__ __forceinline__ void mm64_storeT(const float* __restrict__ A, const float* __restrict__ B,
                                            float* __restrict__ Mt, int tid) {
  const int c0 = (tid >> 4) << 2;
  const int d0 = (tid & 15) << 2;
  float acc[4][4] = {{0.f}};
#pragma unroll
  for (int kb = 0; kb < 64; kb += 4) {
    float4 a[4];
#pragma unroll
    for (int i = 0; i < 4; ++i) a[i] = ldswz4f(A, c0 + i, kb);
#pragma unroll
    for (int r = 0; r < 4; ++r) {
      const float4 q = ldswz4f(B, kb + r, d0);
      const float br[4] = {q.x, q.y, q.z, q.w};
#pragma unroll
      for (int i = 0; i < 4; ++i) {
        const float av = (r == 0) ? a[i].x : (r == 1) ? a[i].y : (r == 2) ? a[i].z : a[i].w;
#pragma unroll
        for (int j = 0; j < 4; ++j) acc[i][j] += av * br[j];
      }
    }
  }
#pragma unroll
  for (int i = 0; i < 4; ++i) {
#pragma unroll
    for (int j = 0; j < 4; ++j) {
      Mt[((d0 + j) << 6) + c0 + i] = acc[i][j];
    }
  }
}

__device__ __forceinline__ void load64x64(const float* __restrict__ g, float* __restrict__ lds, int tid) {
#pragma unroll
  for (int r = 0; r < 4; ++r) {
    const int idx = (r << 8) + tid;
    const int row = idx >> 4;
    const int b4 = (idx & 15) << 2;
    stswz4f(lds, row, b4, *(const float4*)(g + (row << 6) + b4));
  }
}

// ---------------------------------------------------------------------------
// Middle kernel: 8 blocks = 4 batches x 2 sides. Builds logits from G/s,
// softmax, then M (transposed) and c vectors into ws.
__global__ __launch_bounds__(256) void k_mid(
    const float* __restrict__ wq1, const float* __restrict__ bq1,
    const float* __restrict__ wk2, const float* __restrict__ bk2,
    const float* __restrict__ wv2, const float* __restrict__ bv2,
    const float* __restrict__ wo1, const float* __restrict__ bo1,
    const float* __restrict__ wq2, const float* __restrict__ bq2,
    const float* __restrict__ wk1, const float* __restrict__ bk1,
    const float* __restrict__ wv1, const float* __restrict__ bv1,
    const float* __restrict__ wo2, const float* __restrict__ bo2,
    float* __restrict__ ws) {
  __shared__ __align__(16) float LA[4096];
  __shared__ __align__(16) float LB[4096];
  __shared__ __align__(16) float LC[4096];
  __shared__ __align__(16) float LD[4096];
  __shared__ float vsq[64], vsk[64], vaq[64], vkk[64], vcv[64];

  const int tid = threadIdx.x;
  const int b = blockIdx.x >> 1;
  const int side = blockIdx.x & 1;

  const float *Wq, *Bq, *Wk, *Bk, *Wv, *Bv, *Wo, *Bo, *sqp, *skp;
  if (side == 0) {
    Wq = wq1; Bq = bq1; Wk = wk2; Bk = bk2; Wv = wv2; Bv = bv2; Wo = wo1; Bo = bo1;
    sqp = ws + S1_OFF + (b << 6); skp = ws + S2_OFF + (b << 6);
  } else {
    Wq = wq2; Bq = bq2; Wk = wk1; Bk = bk1; Wv = wv1; Bv = bv1; Wo = wo2; Bo = bo2;
    sqp = ws + S2_OFF + (b << 6); skp = ws + S1_OFF + (b << 6);
  }
  float* Mt = ws + MT_OFF + (((side << 2) + b) << 12);
  float* Cv = ws + CV_OFF + (((side << 2) + b) << 6);
  const float* G = ws + G_OFF + (b << 12);

  if (tid < 64) { vsq[tid] = sqp[tid]; vsk[tid] = skp[tid]; }
  load64x64(G, LA, tid);
  load64x64(Wq, LB, tid);
  __syncthreads();
  if (tid < 64) {  // aq = Wq @ sq
    float a = 0.f;
    for (int k = 0; k < 64; ++k) a += ldswz1(LB, tid, k) * vsq[k];
    vaq[tid] = a;
  }
  // T = Wq @ G (side0)  or  Wq @ G^T (side1)
  if (side == 0) mm64<false>(LB, LA, LC, tid);
  else           mm64<true >(LB, LA, LC, tid);
  __syncthreads();
  load64x64(Wk, LB, tid);
  __syncthreads();
  if (tid < 64) {  // kk = Wk @ sk
    float a = 0.f;
    for (int k = 0; k < 64; ++k) a += ldswz1(LB, tid, k) * vsk[k];
    vkk[tid] = a;
  }
  mm64<true>(LC, LB, LD, tid);  // S = T @ Wk^T
  __syncthreads();
  // assemble logits: S = scale*(S + aq[c]*bk[d] + bq[c]*(kk[d] + N*bk[d]))
#pragma unroll
  for (int t = 0; t < 16; ++t) {
    const int idx = (t << 8) + tid;
    const int c = idx >> 6, d = idx & 63;
    const float bkv = Bk[d], bqv = Bq[c];
    float v = ldswz1(LD, c, d);
    v = SCALE * (v + vaq[c] * bkv + bqv * (vkk[d] + 65536.f * bkv));
    stswz1(LD, c, d, v);
  }
  __syncthreads();
  {  // row softmax, 4 lanes per row
    const int row = tid >> 2, q = tid & 3;
    float ev[16];
    float mx = -3.4e38f;
#pragma unroll
    for (int t = 0; t < 16; ++t) { ev[t] = ldswz1(LD, row, q + (t << 2)); mx = fmaxf(mx, ev[t]); }
    mx = fmaxf(mx, __shfl_xor(mx, 1));
    mx = fmaxf(mx, __shfl_xor(mx, 2));
    float sm = 0.f;
#pragma unroll
    for (int t = 0; t < 16; ++t) { ev[t] = __expf(ev[t] - mx); sm += ev[t]; }
    sm += __shfl_xor(sm, 1);
    sm += __shfl_xor(sm, 2);
    const float inv = 1.f / sm;
#pragma unroll
    for (int t = 0; t < 16; ++t) stswz1(LD, row, q + (t << 2), ev[t] * inv);
  }
  __syncthreads();
  if (tid < 64) {  // cv = attn @ bv
    float a = 0.f;
    for (int d = 0; d < 64; ++d) a += ldswz1(LD, tid, d) * Bv[d];
    vcv[tid] = a;
  }
  load64x64(Wv, LB, tid);
  __syncthreads();
  mm64<false>(LD, LB, LC, tid);  // U = attn @ Wv
  __syncthreads();
  load64x64(Wo, LB, tid);
  __syncthreads();
  mm64_storeT(LB, LC, Mt, tid);  // Mt[j][o] = (Wo @ U)[o][j]
  if (tid < 64) {                // c = Wo @ cv + bo
    float a = 0.f;
    for (int c = 0; c < 64; ++c) a += ldswz1(LB, tid, c) * vcv[c];
    Cv[tid] = a + Bo[tid];
  }
}

// ---------------------------------------------------------------------------
// Apply kernel (R6): 2048 blocks = 4 batches x 512 tiles of 128 px.
// 512 thr / 8 waves. Both X tiles (64ch x 128px fp32, 64KB) staged via
// global_load_lds(16B), linear layout. Wave w: side = w>>2, oc = (w&3)*16
// (wave-uniform -> M row is s_load). Lane owns a px-pair: inner loop =
// ds_read_b64 + 16-float M row + 32 FMA; acc[16][2] = 32 VGPR.
__global__ __launch_bounds__(512) void k_apply(const float* __restrict__ x1,
                                               const float* __restrict__ x2,
                                               const float* __restrict__ ws,
                                               float* __restrict__ out) {
  __shared__ __align__(16) float Xs[2][8192];  // [side][ch][128 px]
  const int tid = threadIdx.x;
  const int b = blockIdx.x >> 9;
  const int tile = blockIdx.x & 511;
  const size_t ib = ((size_t)b << 22) + ((size_t)tile << 7);

  const int w = tid >> 6;
  const int l = tid & 63;

  // stage: 32 chunks of 1KB per array; wave w fills chunks 4w..4w+3 of both
#pragma unroll
  for (int q = 0; q < 4; ++q) {
    const int ck = (w << 2) + q;          // 1KB chunk 0..31
    const int c = (ck << 1) | (l >> 5);   // channel row (2 rows per chunk)
    const int p4 = l & 31;                // 16B px-group within row
    const size_t off = ib + ((size_t)c << 16) + (p4 << 2);
    gload_lds16(x1 + off, &Xs[0][ck << 8]);
    gload_lds16(x2 + off, &Xs[1][ck << 8]);
  }
  __syncthreads();  // barrier drains vmcnt -> tiles ready

  const int wu = __builtin_amdgcn_readfirstlane(w);
  const int side = wu >> 2;
  const int oc = (wu & 3) << 4;
  const int job = (side << 2) + b;
  const float* Mt = ws + MT_OFF + ((size_t)job << 12);  // Mt[j][o]
  const float* Cv = ws + CV_OFF + (job << 6);
  const float* Xown = Xs[side];
  const float* Xoth = Xs[side ^ 1];
  const int p0 = l << 1;                  // px pair

  float acc[16][2];
#pragma unroll
  for (int oi = 0; oi < 16; ++oi) {
    const float cb = Cv[oc + oi];
    const float2 xr = *(const float2*)&Xown[((oc + oi) << 7) + p0];
    acc[oi][0] = cb + xr.x;               // bias + residual
    acc[oi][1] = cb + xr.y;
  }

#pragma unroll 2
  for (int j = 0; j < 64; ++j) {
    const float2 xo = *(const float2*)&Xoth[(j << 7) + p0];
    const float* mrow = Mt + (j << 6) + oc;  // wave-uniform -> s_load
#pragma unroll
    for (int oi = 0; oi < 16; ++oi) {
      acc[oi][0] += mrow[oi] * xo.x;
      acc[oi][1] += mrow[oi] * xo.y;
    }
  }

  float* o = out + ((size_t)side << 24) + ib + p0;
#pragma unroll
  for (int oi = 0; oi < 16; ++oi) {
    *(float2*)&o[(size_t)(oc + oi) << 16] = make_float2(acc[oi][0], acc[oi][1]);
  }
}

// ---------------------------------------------------------------------------
extern "C" void kernel_launch(void* const* d_in, const int* in_sizes, int n_in,
                              void* d_out, int out_size, void* d_ws, size_t ws_size,
                              hipStream_t stream) {
  const float* x1 = (const float*)d_in[0];
  const float* x2 = (const float*)d_in[1];
  float* ws = (float*)d_ws;
  float* out = (float*)d_out;

  k_gram<<<NBLK_GRAM, 256, 0, stream>>>(x1, x2, ws + GP_OFF, ws + SP_OFF);
  k_reduce<<<68, 256, 0, stream>>>(ws);
  k_mid<<<8, 256, 0, stream>>>(
      (const float*)d_in[2],  (const float*)d_in[3],   // w_q1, b_q1
      (const float*)d_in[4],  (const float*)d_in[5],   // w_k2, b_k2
      (const float*)d_in[6],  (const float*)d_in[7],   // w_v2, b_v2
      (const float*)d_in[14], (const float*)d_in[15],  // w_o1, b_o1
      (const float*)d_in[8],  (const float*)d_in[9],   // w_q2, b_q2
      (const float*)d_in[10], (const float*)d_in[11],  // w_k1, b_k1
      (const float*)d_in[12], (const float*)d_in[13],  // w_v1, b_v1
      (const float*)d_in[16], (const float*)d_in[17],  // w_o2, b_o2
      ws);
  k_apply<<<2048, 512, 0, stream>>>(x1, x2, ws, out);
}